// Round 1
// baseline (659.116 us; speedup 1.0000x reference)
//
#include <hip/hip_runtime.h>
#include <hip/hip_bf16.h>
#include <stdint.h>

// ---------- types ----------
typedef __attribute__((ext_vector_type(8))) short bf16x8;
typedef __attribute__((ext_vector_type(4))) float f32x4;

#define NB 2
#define NSEQ 2048
#define CDIM 4096
#define NH 32
#define NKV 8
#define HD 128
#define QKV_COLS 6144

static __device__ __forceinline__ unsigned short f2bf(float f) {
    union { float f; unsigned int u; } v; v.f = f;
    unsigned int r = v.u + 0x7fff + ((v.u >> 16) & 1);
    return (unsigned short)(r >> 16);
}
static __device__ __forceinline__ float bf2f(unsigned short b) {
    union { unsigned int u; float f; } v; v.u = ((unsigned int)b) << 16;
    return v.f;
}

static __device__ __forceinline__ void glds16(const void* g, void* l) {
    __builtin_amdgcn_global_load_lds(
        (const __attribute__((address_space(1))) void*)g,
        (__attribute__((address_space(3))) void*)l, 16, 0, 0);
}

// ---------- 1) f32 -> bf16 convert (input + weight) ----------
__global__ void convert_kernel(const float* __restrict__ inA, const float* __restrict__ inW,
                               unsigned short* __restrict__ outA, unsigned short* __restrict__ outW) {
    const long long nA4 = (long long)CDIM * (NB * NSEQ) / 4;       // 4,194,304
    const long long nW4 = (long long)QKV_COLS * CDIM / 4;          // 6,291,456
    const long long total = nA4 + nW4;
    for (long long i = blockIdx.x * 256LL + threadIdx.x; i < total; i += (long long)gridDim.x * 256LL) {
        const float4* src; unsigned short* dst; long long j;
        if (i < nA4) { src = (const float4*)inA; dst = outA; j = i; }
        else         { src = (const float4*)inW; dst = outW; j = i - nA4; }
        float4 v = src[j];
        ushort4 o;
        o.x = f2bf(v.x); o.y = f2bf(v.y); o.z = f2bf(v.z); o.w = f2bf(v.w);
        ((ushort4*)dst)[j] = o;
    }
}

// ---------- 2) QKV GEMM: C[M=4096][6144] = A[4096][4096] * W[6144][4096]^T ----------
// 128x128 tile, BK=64, 4 waves (2x2), each wave 64x64 via 4x4 frags of 16x16x32 MFMA.
// LDS tiles [128 rows][128 bytes], XOR-swizzled via pre-swizzled global source.
__global__ __launch_bounds__(256) void gemm_qkv(
    const unsigned short* __restrict__ A, const unsigned short* __restrict__ W,
    unsigned short* __restrict__ qb, unsigned short* __restrict__ kb, unsigned short* __restrict__ vt)
{
    __shared__ unsigned char a_tile[16384];
    __shared__ unsigned char w_tile[16384];

    const int bid = blockIdx.x;
    const int bm = bid % 32;          // M tile (rows of A)
    const int bn = bid / 32;          // col tile (rows of W) 0..47
    const int t = threadIdx.x;
    const int l = t & 63, w = t >> 6;
    const int wr = w >> 1, wc = w & 1;

    f32x4 acc[4][4] = {};

    for (int kt = 0; kt < CDIM / 64; ++kt) {
#pragma unroll
        for (int i = 0; i < 4; ++i) {
            int byte = (i * 256 + t) * 16;
            int r = byte >> 7;            // tile row (128B rows)
            int c = byte & 127;
            int cs = c ^ ((r & 7) << 4);  // pre-swizzled source column bytes
            glds16(A + (long long)(bm * 128 + r) * CDIM + kt * 64 + (cs >> 1), a_tile + byte);
            glds16(W + (long long)(bn * 128 + r) * CDIM + kt * 64 + (cs >> 1), w_tile + byte);
        }
        __syncthreads();
#pragma unroll
        for (int dc = 0; dc < 2; ++dc) {
            bf16x8 af[4], bfr[4];
#pragma unroll
            for (int i = 0; i < 4; ++i) {
                int row = wr * 64 + i * 16 + (l & 15);
                int cb = (dc * 64 + ((l >> 4) << 4)) ^ ((row & 7) << 4);
                af[i] = *(const bf16x8*)(a_tile + row * 128 + cb);
            }
#pragma unroll
            for (int j = 0; j < 4; ++j) {
                int row = wc * 64 + j * 16 + (l & 15);
                int cb = (dc * 64 + ((l >> 4) << 4)) ^ ((row & 7) << 4);
                bfr[j] = *(const bf16x8*)(w_tile + row * 128 + cb);
            }
#pragma unroll
            for (int i = 0; i < 4; ++i)
#pragma unroll
                for (int j = 0; j < 4; ++j)
                    acc[i][j] = __builtin_amdgcn_mfma_f32_16x16x32_bf16(af[i], bfr[j], acc[i][j], 0, 0, 0);
        }
        __syncthreads();
    }

    // epilogue: scatter into q [B,NH,N,D], k [B,NKV,N,D], v^T [B,NKV,D,N], all bf16
#pragma unroll
    for (int i = 0; i < 4; ++i) {
#pragma unroll
        for (int j = 0; j < 4; ++j) {
#pragma unroll
            for (int r = 0; r < 4; ++r) {
                int m = bm * 128 + wr * 64 + i * 16 + ((l >> 4) << 2) + r;
                int col = wc * 64 + j * 16 + (l & 15);   // 0..127 within tile == d
                int b = m >> 11, n = m & 2047;
                unsigned short hv = f2bf(acc[i][j][r]);
                if (bn < 32) {
                    qb[(((b * NH + bn) * NSEQ + n) << 7) + col] = hv;
                } else if (bn < 40) {
                    kb[(((b * NKV + (bn - 32)) * NSEQ + n) << 7) + col] = hv;
                } else {
                    vt[(((b * NKV + (bn - 40)) * HD + col) << 11) + n] = hv;
                }
            }
        }
    }
}

// ---------- 3) RoPE (in-place on q,k; folds 1/sqrt(128) into q) ----------
__global__ void rope_kernel(unsigned short* __restrict__ qb, unsigned short* __restrict__ kb,
                            const float* __restrict__ cosc, const float* __restrict__ sinc,
                            const int* __restrict__ pos) {
    int rowid = blockIdx.x * 4 + (threadIdx.x >> 6);
    int d = threadIdx.x & 63;
    int b = rowid / (40 * NSEQ);
    int rem = rowid % (40 * NSEQ);
    int head = rem / NSEQ, n = rem % NSEQ;
    unsigned short* p;
    float scale;
    if (head < NH) { p = qb + (((long long)(b * NH + head) * NSEQ + n) << 7); scale = 0.08838834764831845f; }
    else           { p = kb + (((long long)(b * NKV + (head - NH)) * NSEQ + n) << 7); scale = 1.0f; }
    int pid = pos[b * NSEQ + n];
    float c = cosc[pid * HD + d], s = sinc[pid * HD + d];
    float x0 = bf2f(p[d]), x1 = bf2f(p[d + 64]);
    p[d]      = f2bf((x0 * c - x1 * s) * scale);
    p[d + 64] = f2bf((x1 * c + x0 * s) * scale);
}

// ---------- 4) flash attention, causal, GQA ----------
// block = (b, h, 64 q rows); 4 waves x 16 rows; KV tile = 64.
__global__ __launch_bounds__(256) void attn_kernel(
    const unsigned short* __restrict__ qb, const unsigned short* __restrict__ kb,
    const unsigned short* __restrict__ vt, const int* __restrict__ obs,
    float* __restrict__ out)
{
    __shared__ unsigned char k_tile[16384];   // [64 kv][128 d] bf16, 256B rows, swizzled
    __shared__ unsigned char v_tile[16384];   // [128 d][64 kv] bf16, 128B rows, swizzled
    __shared__ unsigned char p_lds[8192];     // per-wave 16x64 bf16, swizzled

    const int bid = blockIdx.x;
    const int qt = bid & 31;
    const int h = (bid >> 5) & 31;
    const int b = bid >> 10;
    const int kvh = h >> 2;
    const int t = threadIdx.x, l = t & 63, w = t >> 6;

    const unsigned short* Qb = qb + (((long long)(b * NH + h) * NSEQ + qt * 64 + w * 16) << 7);
    const unsigned short* Kb = kb + (((long long)(b * NKV + kvh) * NSEQ) << 7);
    const unsigned short* Vb = vt + (((long long)(b * NKV + kvh) * HD) << 11);

    bf16x8 qf[4];
#pragma unroll
    for (int dc = 0; dc < 4; ++dc)
        qf[dc] = *(const bf16x8*)(Qb + ((l & 15) << 7) + dc * 32 + ((l >> 4) << 3));

    f32x4 o_acc[8] = {};
    float m_run[4], l_run[4];
#pragma unroll
    for (int r = 0; r < 4; ++r) { m_run[r] = -1e30f; l_run[r] = 0.f; }

    unsigned char* pw = p_lds + w * 2048;

    for (int kt = 0; kt <= qt; ++kt) {
#pragma unroll
        for (int i = 0; i < 4; ++i) {
            int byte = (i * 256 + t) * 16;
            {   // K tile: rows 256B
                int r = byte >> 8, c = byte & 255;
                int cs = c ^ ((r & 7) << 4);
                glds16(Kb + ((long long)(kt * 64 + r) << 7) + (cs >> 1), k_tile + byte);
            }
            {   // Vt tile: rows 128B
                int r = byte >> 7, c = byte & 127;
                int cs = c ^ ((r & 7) << 4);
                glds16(Vb + ((long long)r << 11) + kt * 64 + (cs >> 1), v_tile + byte);
            }
        }
        __syncthreads();

        // S = Q K^T   (16q x 64kv per wave)
        f32x4 sa[4];
#pragma unroll
        for (int jf = 0; jf < 4; ++jf) {
            f32x4 z = {};
#pragma unroll
            for (int dc = 0; dc < 4; ++dc) {
                int row = jf * 16 + (l & 15);
                int cb = (dc * 64 + ((l >> 4) << 4)) ^ ((row & 7) << 4);
                bf16x8 kf = *(const bf16x8*)(k_tile + (row << 8) + cb);
                z = __builtin_amdgcn_mfma_f32_16x16x32_bf16(qf[dc], kf, z, 0, 0, 0);
            }
            sa[jf] = z;
        }

        if (kt == qt) {  // causal mask on diagonal tile
#pragma unroll
            for (int jf = 0; jf < 4; ++jf)
#pragma unroll
                for (int r = 0; r < 4; ++r) {
                    int qrow = w * 16 + ((l >> 4) << 2) + r;
                    int kvcol = jf * 16 + (l & 15);
                    if (kvcol > qrow) sa[jf][r] = -1e30f;
                }
        }

        // online softmax
        float scale_[4];
        float pv[4][4];
#pragma unroll
        for (int r = 0; r < 4; ++r) {
            float mx = fmaxf(fmaxf(sa[0][r], sa[1][r]), fmaxf(sa[2][r], sa[3][r]));
#pragma unroll
            for (int off = 8; off; off >>= 1) mx = fmaxf(mx, __shfl_xor(mx, off, 16));
            float mnew = fmaxf(m_run[r], mx);
            scale_[r] = __expf(m_run[r] - mnew);
            float sum = 0.f;
#pragma unroll
            for (int jf = 0; jf < 4; ++jf) {
                float p = __expf(sa[jf][r] - mnew);
                pv[jf][r] = p;
                sum += p;
            }
#pragma unroll
            for (int off = 8; off; off >>= 1) sum += __shfl_xor(sum, off, 16);
            l_run[r] = l_run[r] * scale_[r] + sum;
            m_run[r] = mnew;
        }

#pragma unroll
        for (int jd = 0; jd < 8; ++jd)
#pragma unroll
            for (int r = 0; r < 4; ++r) o_acc[jd][r] *= scale_[r];

        // P -> per-wave LDS (bf16, swizzled) for transpose into A-operand layout
#pragma unroll
        for (int jf = 0; jf < 4; ++jf)
#pragma unroll
            for (int r = 0; r < 4; ++r) {
                int qrow = ((l >> 4) << 2) + r;
                int col2 = (jf * 16 + (l & 15)) * 2;
                *(unsigned short*)(pw + (qrow << 7) + (col2 ^ ((qrow & 7) << 4))) = f2bf(pv[jf][r]);
            }

        // O += P V
#pragma unroll
        for (int kc = 0; kc < 2; ++kc) {
            int cbp = kc * 64 + ((l >> 4) << 4);
            bf16x8 pa = *(const bf16x8*)(pw + ((l & 15) << 7) + (cbp ^ (((l & 15) & 7) << 4)));
#pragma unroll
            for (int jd = 0; jd < 8; ++jd) {
                int row = jd * 16 + (l & 15);
                int cb = cbp ^ ((row & 7) << 4);
                bf16x8 vf = *(const bf16x8*)(v_tile + (row << 7) + cb);
                o_acc[jd] = __builtin_amdgcn_mfma_f32_16x16x32_bf16(pa, vf, o_acc[jd], 0, 0, 0);
            }
        }
        __syncthreads();
    }

    // epilogue: out[b*N+n][h*128+d] f32, masked by observation_mask
#pragma unroll
    for (int r = 0; r < 4; ++r) {
        int n = qt * 64 + w * 16 + ((l >> 4) << 2) + r;
        float inv = 1.0f / l_run[r];
        float mf = (obs[b * NSEQ + n] == 1) ? 1.0f : 0.0f;
        long long orow = ((long long)(b * NSEQ + n)) << 12;
#pragma unroll
        for (int jd = 0; jd < 8; ++jd)
            out[orow + h * HD + jd * 16 + (l & 15)] = o_acc[jd][r] * inv * mf;
    }
}

// ---------- launch ----------
extern "C" void kernel_launch(void* const* d_in, const int* in_sizes, int n_in,
                              void* d_out, int out_size, void* d_ws, size_t ws_size,
                              hipStream_t stream) {
    (void)in_sizes; (void)n_in; (void)out_size; (void)ws_size;
    const float* inp  = (const float*)d_in[0];
    const float* wgt  = (const float*)d_in[1];
    const float* cosc = (const float*)d_in[2];
    const float* sinc = (const float*)d_in[3];
    // d_in[4] = attention_mask (exact causal; implemented analytically)
    const int* pos = (const int*)d_in[5];
    const int* obs = (const int*)d_in[6];
    float* out = (float*)d_out;

    char* ws = (char*)d_ws;
    unsigned short* A16 = (unsigned short*)(ws);                    // 33,554,432 B
    unsigned short* W16 = (unsigned short*)(ws + 33554432LL);       // 50,331,648 B
    unsigned short* qb  = (unsigned short*)(ws + 83886080LL);       // 33,554,432 B
    unsigned short* kb  = (unsigned short*)(ws + 117440512LL);      //  8,388,608 B
    unsigned short* vt  = (unsigned short*)(ws + 125829120LL);      //  8,388,608 B  (total 128 MB)

    convert_kernel<<<2048, 256, 0, stream>>>(inp, wgt, A16, W16);
    gemm_qkv<<<32 * 48, 256, 0, stream>>>(A16, W16, qb, kb, vt);
    rope_kernel<<<(2 * 40 * NSEQ) / 4, 256, 0, stream>>>(qb, kb, cosc, sinc, pos);
    attn_kernel<<<NB * NH * (NSEQ / 64), 256, 0, stream>>>(qb, kb, vt, obs, out);
}

// Round 2
// 450.870 us; speedup vs baseline: 1.4619x; 1.4619x over previous
//
#include <hip/hip_runtime.h>
#include <hip/hip_bf16.h>
#include <stdint.h>

// ---------- types ----------
typedef __attribute__((ext_vector_type(8))) short bf16x8;
typedef __attribute__((ext_vector_type(4))) float f32x4;
typedef __attribute__((ext_vector_type(16))) float f32x16;

#define NB 2
#define NSEQ 2048
#define CDIM 4096
#define NH 32
#define NKV 8
#define HD 128
#define QKV_COLS 6144

static __device__ __forceinline__ unsigned short f2bf(float f) {
    union { float f; unsigned int u; } v; v.f = f;
    unsigned int r = v.u + 0x7fff + ((v.u >> 16) & 1);
    return (unsigned short)(r >> 16);
}
static __device__ __forceinline__ float bf2f(unsigned short b) {
    union { unsigned int u; float f; } v; v.u = ((unsigned int)b) << 16;
    return v.f;
}

static __device__ __forceinline__ void glds16(const void* g, void* l) {
    __builtin_amdgcn_global_load_lds(
        (const __attribute__((address_space(1))) void*)g,
        (__attribute__((address_space(3))) void*)l, 16, 0, 0);
}

static __device__ __forceinline__ unsigned cvtpk(float a, float b) {
    unsigned r; asm("v_cvt_pk_bf16_f32 %0, %1, %2" : "=v"(r) : "v"(a), "v"(b));
    return r;
}

// pack one 32-kv P-tile (16 f32/lane, swapped-QK layout) into two PV B-frags
static __device__ __forceinline__ void pack_tile(const f32x16& p, int l, bf16x8& fa, bf16x8& fb) {
    unsigned a0 = cvtpk(p[0], p[1]),   b0 = cvtpk(p[4], p[5]);
    unsigned a1 = cvtpk(p[2], p[3]),   b1 = cvtpk(p[6], p[7]);
    unsigned a2 = cvtpk(p[8], p[9]),   b2 = cvtpk(p[12], p[13]);
    unsigned a3 = cvtpk(p[10], p[11]), b3 = cvtpk(p[14], p[15]);
    union U { unsigned u[4]; bf16x8 v; } ua, ub;
#if __has_builtin(__builtin_amdgcn_permlane32_swap)
    auto r0 = __builtin_amdgcn_permlane32_swap(a0, b0, false, false);
    auto r1 = __builtin_amdgcn_permlane32_swap(a1, b1, false, false);
    auto r2 = __builtin_amdgcn_permlane32_swap(a2, b2, false, false);
    auto r3 = __builtin_amdgcn_permlane32_swap(a3, b3, false, false);
    ua.u[0] = r0[0]; ua.u[1] = r1[0]; ua.u[2] = r0[1]; ua.u[3] = r1[1];
    ub.u[0] = r2[0]; ub.u[1] = r3[0]; ub.u[2] = r2[1]; ub.u[3] = r3[1];
#else
    unsigned a0t = __shfl_xor(a0, 32), b0t = __shfl_xor(b0, 32);
    unsigned a1t = __shfl_xor(a1, 32), b1t = __shfl_xor(b1, 32);
    unsigned a2t = __shfl_xor(a2, 32), b2t = __shfl_xor(b2, 32);
    unsigned a3t = __shfl_xor(a3, 32), b3t = __shfl_xor(b3, 32);
    bool lo = (l < 32);
    ua.u[0] = lo ? a0 : b0t; ua.u[1] = lo ? a1 : b1t; ua.u[2] = lo ? a0t : b0; ua.u[3] = lo ? a1t : b1;
    ub.u[0] = lo ? a2 : b2t; ub.u[1] = lo ? a3 : b3t; ub.u[2] = lo ? a2t : b2; ub.u[3] = lo ? a3t : b3;
#endif
    fa = ua.v; fb = ub.v;
}

// ---------- 1) f32 -> bf16 convert (input + weight) ----------
__global__ void convert_kernel(const float* __restrict__ inA, const float* __restrict__ inW,
                               unsigned short* __restrict__ outA, unsigned short* __restrict__ outW) {
    const long long nA4 = (long long)CDIM * (NB * NSEQ) / 4;
    const long long nW4 = (long long)QKV_COLS * CDIM / 4;
    const long long total = nA4 + nW4;
    for (long long i = blockIdx.x * 256LL + threadIdx.x; i < total; i += (long long)gridDim.x * 256LL) {
        const float4* src; unsigned short* dst; long long j;
        if (i < nA4) { src = (const float4*)inA; dst = outA; j = i; }
        else         { src = (const float4*)inW; dst = outW; j = i - nA4; }
        float4 v = src[j];
        ushort4 o;
        o.x = f2bf(v.x); o.y = f2bf(v.y); o.z = f2bf(v.z); o.w = f2bf(v.w);
        ((ushort4*)dst)[j] = o;
    }
}

// ---------- 2) QKV GEMM ----------
__global__ __launch_bounds__(256) void gemm_qkv(
    const unsigned short* __restrict__ A, const unsigned short* __restrict__ W,
    unsigned short* __restrict__ qb, unsigned short* __restrict__ kb, unsigned short* __restrict__ vt)
{
    __shared__ unsigned char a_tile[16384];
    __shared__ unsigned char w_tile[16384];

    const int bid = blockIdx.x;
    const int bm = bid % 32;
    const int bn = bid / 32;
    const int t = threadIdx.x;
    const int l = t & 63, w = t >> 6;
    const int wr = w >> 1, wc = w & 1;

    f32x4 acc[4][4] = {};

    for (int kt = 0; kt < CDIM / 64; ++kt) {
#pragma unroll
        for (int i = 0; i < 4; ++i) {
            int byte = (i * 256 + t) * 16;
            int r = byte >> 7;
            int c = byte & 127;
            int cs = c ^ ((r & 7) << 4);
            glds16(A + (long long)(bm * 128 + r) * CDIM + kt * 64 + (cs >> 1), a_tile + byte);
            glds16(W + (long long)(bn * 128 + r) * CDIM + kt * 64 + (cs >> 1), w_tile + byte);
        }
        __syncthreads();
#pragma unroll
        for (int dc = 0; dc < 2; ++dc) {
            bf16x8 af[4], bfr[4];
#pragma unroll
            for (int i = 0; i < 4; ++i) {
                int row = wr * 64 + i * 16 + (l & 15);
                int cb = (dc * 64 + ((l >> 4) << 4)) ^ ((row & 7) << 4);
                af[i] = *(const bf16x8*)(a_tile + row * 128 + cb);
            }
#pragma unroll
            for (int j = 0; j < 4; ++j) {
                int row = wc * 64 + j * 16 + (l & 15);
                int cb = (dc * 64 + ((l >> 4) << 4)) ^ ((row & 7) << 4);
                bfr[j] = *(const bf16x8*)(w_tile + row * 128 + cb);
            }
#pragma unroll
            for (int i = 0; i < 4; ++i)
#pragma unroll
                for (int j = 0; j < 4; ++j)
                    acc[i][j] = __builtin_amdgcn_mfma_f32_16x16x32_bf16(af[i], bfr[j], acc[i][j], 0, 0, 0);
        }
        __syncthreads();
    }

#pragma unroll
    for (int i = 0; i < 4; ++i) {
#pragma unroll
        for (int j = 0; j < 4; ++j) {
#pragma unroll
            for (int r = 0; r < 4; ++r) {
                int m = bm * 128 + wr * 64 + i * 16 + ((l >> 4) << 2) + r;
                int col = wc * 64 + j * 16 + (l & 15);
                int b = m >> 11, n = m & 2047;
                unsigned short hv = f2bf(acc[i][j][r]);
                if (bn < 32) {
                    qb[(((b * NH + bn) * NSEQ + n) << 7) + col] = hv;
                } else if (bn < 40) {
                    kb[(((b * NKV + (bn - 32)) * NSEQ + n) << 7) + col] = hv;
                } else {
                    vt[(((b * NKV + (bn - 40)) * HD + col) << 11) + n] = hv;
                }
            }
        }
    }
}

// ---------- 3) RoPE (folds log2e/sqrt(128) into q for exp2-domain softmax) ----------
__global__ void rope_kernel(unsigned short* __restrict__ qb, unsigned short* __restrict__ kb,
                            const float* __restrict__ cosc, const float* __restrict__ sinc,
                            const int* __restrict__ pos) {
    int rowid = blockIdx.x * 4 + (threadIdx.x >> 6);
    int d = threadIdx.x & 63;
    int b = rowid / (40 * NSEQ);
    int rem = rowid % (40 * NSEQ);
    int head = rem / NSEQ, n = rem % NSEQ;
    unsigned short* p;
    float scale;
    if (head < NH) { p = qb + (((long long)(b * NH + head) * NSEQ + n) << 7); scale = 0.12751747934e0f; } // log2(e)/sqrt(128)
    else           { p = kb + (((long long)(b * NKV + (head - NH)) * NSEQ + n) << 7); scale = 1.0f; }
    int pid = pos[b * NSEQ + n];
    float c = cosc[pid * HD + d], s = sinc[pid * HD + d];
    float x0 = bf2f(p[d]), x1 = bf2f(p[d + 64]);
    p[d]      = f2bf((x0 * c - x1 * s) * scale);
    p[d + 64] = f2bf((x1 * c + x0 * s) * scale);
}

// ---------- 4) flash attention: 4 waves x 32 q-rows, swapped QK^T, in-reg softmax ----------
__global__ __launch_bounds__(256) void attn_kernel(
    const unsigned short* __restrict__ qb, const unsigned short* __restrict__ kb,
    const unsigned short* __restrict__ vt, const int* __restrict__ obs,
    float* __restrict__ out)
{
    __shared__ unsigned char k_tile[16384];   // [64 kv][128 d] bf16, swizzled
    __shared__ unsigned char v_tile[16384];   // [128 d][64 kv] bf16, swizzled

    const int bid = blockIdx.x;
    const int qt = 15 - (bid >> 6);           // descending: longest blocks dispatch first
    const int bh = bid & 63;
    const int b = bh >> 5, h = bh & 31, kvh = h >> 2;
    const int t = threadIdx.x, l = t & 63, w = t >> 6;
    const int lr = l & 31, hi = l >> 5;
    const int swl = (l & 7) << 4;             // XOR swizzle term (row&7 == l&7 for all our reads)

    const unsigned short* Qb = qb + (((long long)(b * NH + h) * NSEQ + qt * 128 + w * 32) << 7);
    const unsigned short* Kb = kb + (((long long)(b * NKV + kvh) * NSEQ) << 7);
    const unsigned short* Vb = vt + (((long long)(b * NKV + kvh) * HD) << 11);

    // Q fragments: B-operand of mfma(K,Q): lane holds q-row lr, d = dk*16 + hi*8 + e
    bf16x8 qf[8];
#pragma unroll
    for (int dk = 0; dk < 8; ++dk)
        qf[dk] = *(const bf16x8*)(Qb + lr * 128 + dk * 16 + hi * 8);

    f32x16 o[4];
#pragma unroll
    for (int dt = 0; dt < 4; ++dt)
#pragma unroll
        for (int e = 0; e < 16; ++e) o[dt][e] = 0.f;
    float m_run = -1e30f, l_run = 0.f;

    const int qwmax = qt * 128 + w * 32 + 31;
    const int niter = 2 * qt + 2;

    for (int kt = 0; kt < niter; ++kt) {
        // ---- stage K,V tile (glds, pre-swizzled source) ----
#pragma unroll
        for (int i = 0; i < 4; ++i) {
            int byte = (i * 256 + t) * 16;
            { int r = byte >> 8, c = byte & 255; int cs = c ^ ((r & 7) << 4);
              glds16(Kb + (((long long)(kt * 64 + r)) << 7) + (cs >> 1), k_tile + byte); }
            { int r = byte >> 7, c = byte & 127; int cs = c ^ ((r & 7) << 4);
              glds16(Vb + (((long long)r) << 11) + kt * 64 + (cs >> 1), v_tile + byte); }
        }
        __syncthreads();

        if (kt * 64 <= qwmax) {   // wave-level causal skip
            // ---- S^T = K · Q^T (two 32x32 tiles over kv64) ----
            f32x16 s0, s1;
#pragma unroll
            for (int e = 0; e < 16; ++e) { s0[e] = 0.f; s1[e] = 0.f; }
            __builtin_amdgcn_s_setprio(1);
#pragma unroll
            for (int dk = 0; dk < 8; ++dk) {
                int cb = (dk * 32 + hi * 16) ^ swl;
                bf16x8 k0 = *(const bf16x8*)(k_tile + lr * 256 + cb);
                bf16x8 k1 = *(const bf16x8*)(k_tile + (32 + lr) * 256 + cb);
                s0 = __builtin_amdgcn_mfma_f32_32x32x16_bf16(k0, qf[dk], s0, 0, 0, 0);
                s1 = __builtin_amdgcn_mfma_f32_32x32x16_bf16(k1, qf[dk], s1, 0, 0, 0);
            }
            __builtin_amdgcn_s_setprio(0);

            // ---- causal mask (diagonal-adjacent tiles only) ----
            if (kt * 64 + 63 > qt * 128 + w * 32) {
                int qg = qt * 128 + w * 32 + lr;
                int base = kt * 64 + hi * 4;
#pragma unroll
                for (int e = 0; e < 16; ++e) {
                    int kv0 = base + (e & 3) + 8 * (e >> 2);
                    if (kv0 > qg)      s0[e] = -1e30f;
                    if (kv0 + 32 > qg) s1[e] = -1e30f;
                }
            }

            // ---- online softmax (exp2 domain; row is lane-local + one cross-half shfl) ----
            float mloc = fmaxf(s0[0], s0[1]);
#pragma unroll
            for (int e = 2; e < 16; ++e) mloc = fmaxf(mloc, s0[e]);
#pragma unroll
            for (int e = 0; e < 16; ++e) mloc = fmaxf(mloc, s1[e]);
            mloc = fmaxf(mloc, __shfl_xor(mloc, 32));

            float mm = m_run;
            if (!__all(mloc - m_run <= 8.f)) {   // defer-max (T13)
                mm = fmaxf(m_run, mloc);
                float sc = __builtin_amdgcn_exp2f(m_run - mm);
                l_run *= sc;
#pragma unroll
                for (int dt = 0; dt < 4; ++dt)
#pragma unroll
                    for (int e = 0; e < 16; ++e) o[dt][e] *= sc;
                m_run = mm;
            }
            float sum = 0.f;
#pragma unroll
            for (int e = 0; e < 16; ++e) { s0[e] = __builtin_amdgcn_exp2f(s0[e] - mm); sum += s0[e]; }
#pragma unroll
            for (int e = 0; e < 16; ++e) { s1[e] = __builtin_amdgcn_exp2f(s1[e] - mm); sum += s1[e]; }
            sum += __shfl_xor(sum, 32);
            l_run += sum;

            // ---- P -> bf16 B-frags in-register (T12) ----
            bf16x8 pb[4];
            pack_tile(s0, l, pb[0], pb[1]);
            pack_tile(s1, l, pb[2], pb[3]);

            // ---- O^T += V^T · P^T ----
            __builtin_amdgcn_s_setprio(1);
#pragma unroll
            for (int dt = 0; dt < 4; ++dt) {
#pragma unroll
                for (int kk = 0; kk < 4; ++kk) {
                    int cb = (kk * 32 + hi * 16) ^ swl;
                    bf16x8 vf = *(const bf16x8*)(v_tile + (dt * 32 + lr) * 128 + cb);
                    o[dt] = __builtin_amdgcn_mfma_f32_32x32x16_bf16(vf, pb[kk], o[dt], 0, 0, 0);
                }
            }
            __builtin_amdgcn_s_setprio(0);
        }
        __syncthreads();
    }

    // ---- epilogue: normalize, mask, transpose via per-wave LDS slice, coalesced f32x4 stores ----
    {
        int n = qt * 128 + w * 32 + lr;
        float fac = (1.f / l_run) * ((obs[b * NSEQ + n] == 1) ? 1.f : 0.f);
        unsigned char* slice = k_tile + w * 4096;   // 4KB per wave, no cross-wave sharing
        int q2 = l >> 1, half = l & 1;
        long long orow = ((long long)(b * NSEQ + qt * 128 + w * 32 + q2)) << 12;
#pragma unroll
        for (int dt = 0; dt < 4; ++dt) {
#pragma unroll
            for (int e = 0; e < 16; e += 2) {
                int dl = (e & 3) + 8 * (e >> 2) + hi * 4;
                int byte = (lr * 128 + dl * 4) ^ ((lr & 7) << 4);
                *(float2*)(slice + byte) = make_float2(o[dt][e] * fac, o[dt][e + 1] * fac);
            }
            // within-wave ds_write -> ds_read; compiler inserts lgkmcnt
#pragma unroll
            for (int j = 0; j < 4; ++j) {
                int byte = (q2 * 128 + half * 64 + j * 16) ^ ((q2 & 7) << 4);
                f32x4 vv = *(const f32x4*)(slice + byte);
                *(f32x4*)(out + orow + h * 128 + dt * 32 + half * 16 + j * 4) = vv;
            }
            __syncthreads();   // slice reused next dt by this wave only; barrier keeps waves' LDS quiescent cheaply
        }
    }
}

// ---------- launch ----------
extern "C" void kernel_launch(void* const* d_in, const int* in_sizes, int n_in,
                              void* d_out, int out_size, void* d_ws, size_t ws_size,
                              hipStream_t stream) {
    (void)in_sizes; (void)n_in; (void)out_size; (void)ws_size;
    const float* inp  = (const float*)d_in[0];
    const float* wgt  = (const float*)d_in[1];
    const float* cosc = (const float*)d_in[2];
    const float* sinc = (const float*)d_in[3];
    const int* pos = (const int*)d_in[5];
    const int* obs = (const int*)d_in[6];
    float* out = (float*)d_out;

    char* ws = (char*)d_ws;
    unsigned short* A16 = (unsigned short*)(ws);
    unsigned short* W16 = (unsigned short*)(ws + 33554432LL);
    unsigned short* qb  = (unsigned short*)(ws + 83886080LL);
    unsigned short* kb  = (unsigned short*)(ws + 117440512LL);
    unsigned short* vt  = (unsigned short*)(ws + 125829120LL);

    convert_kernel<<<2048, 256, 0, stream>>>(inp, wgt, A16, W16);
    gemm_qkv<<<32 * 48, 256, 0, stream>>>(A16, W16, qb, kb, vt);
    rope_kernel<<<(2 * 40 * NSEQ) / 4, 256, 0, stream>>>(qb, kb, cosc, sinc, pos);
    attn_kernel<<<16 * 64, 256, 0, stream>>>(qb, kb, vt, obs, out);
}

// Round 3
// 417.296 us; speedup vs baseline: 1.5795x; 1.0805x over previous
//
#include <hip/hip_runtime.h>
#include <hip/hip_bf16.h>
#include <stdint.h>

// ---------- types ----------
typedef __attribute__((ext_vector_type(8))) short bf16x8;
typedef __attribute__((ext_vector_type(4))) float f32x4;
typedef __attribute__((ext_vector_type(16))) float f32x16;

#define NB 2
#define NSEQ 2048
#define CDIM 4096
#define NH 32
#define NKV 8
#define HD 128
#define QKV_COLS 6144

static __device__ __forceinline__ unsigned short f2bf(float f) {
    union { float f; unsigned int u; } v; v.f = f;
    unsigned int r = v.u + 0x7fff + ((v.u >> 16) & 1);
    return (unsigned short)(r >> 16);
}
static __device__ __forceinline__ float bf2f(unsigned short b) {
    union { unsigned int u; float f; } v; v.u = ((unsigned int)b) << 16;
    return v.f;
}

static __device__ __forceinline__ void glds16(const void* g, void* l) {
    __builtin_amdgcn_global_load_lds(
        (const __attribute__((address_space(1))) void*)g,
        (__attribute__((address_space(3))) void*)l, 16, 0, 0);
}

static __device__ __forceinline__ unsigned cvtpk(float a, float b) {
    unsigned r; asm("v_cvt_pk_bf16_f32 %0, %1, %2" : "=v"(r) : "v"(a), "v"(b));
    return r;
}

static __device__ __forceinline__ void pack_tile(const f32x16& p, int l, bf16x8& fa, bf16x8& fb) {
    unsigned a0 = cvtpk(p[0], p[1]),   b0 = cvtpk(p[4], p[5]);
    unsigned a1 = cvtpk(p[2], p[3]),   b1 = cvtpk(p[6], p[7]);
    unsigned a2 = cvtpk(p[8], p[9]),   b2 = cvtpk(p[12], p[13]);
    unsigned a3 = cvtpk(p[10], p[11]), b3 = cvtpk(p[14], p[15]);
    union U { unsigned u[4]; bf16x8 v; } ua, ub;
#if __has_builtin(__builtin_amdgcn_permlane32_swap)
    auto r0 = __builtin_amdgcn_permlane32_swap(a0, b0, false, false);
    auto r1 = __builtin_amdgcn_permlane32_swap(a1, b1, false, false);
    auto r2 = __builtin_amdgcn_permlane32_swap(a2, b2, false, false);
    auto r3 = __builtin_amdgcn_permlane32_swap(a3, b3, false, false);
    ua.u[0] = r0[0]; ua.u[1] = r1[0]; ua.u[2] = r0[1]; ua.u[3] = r1[1];
    ub.u[0] = r2[0]; ub.u[1] = r3[0]; ub.u[2] = r2[1]; ub.u[3] = r3[1];
#else
    unsigned a0t = __shfl_xor(a0, 32), b0t = __shfl_xor(b0, 32);
    unsigned a1t = __shfl_xor(a1, 32), b1t = __shfl_xor(b1, 32);
    unsigned a2t = __shfl_xor(a2, 32), b2t = __shfl_xor(b2, 32);
    unsigned a3t = __shfl_xor(a3, 32), b3t = __shfl_xor(b3, 32);
    bool lo = (l < 32);
    ua.u[0] = lo ? a0 : b0t; ua.u[1] = lo ? a1 : b1t; ua.u[2] = lo ? a0t : b0; ua.u[3] = lo ? a1t : b1;
    ub.u[0] = lo ? a2 : b2t; ub.u[1] = lo ? a3 : b3t; ub.u[2] = lo ? a2t : b2; ub.u[3] = lo ? a3t : b3;
#endif
    fa = ua.v; fb = ub.v;
}

// ---------- 1) f32 -> bf16 convert ----------
__global__ void convert_kernel(const float* __restrict__ inA, const float* __restrict__ inW,
                               unsigned short* __restrict__ outA, unsigned short* __restrict__ outW) {
    const long long nA4 = (long long)CDIM * (NB * NSEQ) / 4;
    const long long nW4 = (long long)QKV_COLS * CDIM / 4;
    const long long total = nA4 + nW4;
    for (long long i = blockIdx.x * 256LL + threadIdx.x; i < total; i += (long long)gridDim.x * 256LL) {
        const float4* src; unsigned short* dst; long long j;
        if (i < nA4) { src = (const float4*)inA; dst = outA; j = i; }
        else         { src = (const float4*)inW; dst = outW; j = i - nA4; }
        float4 v = src[j];
        ushort4 o;
        o.x = f2bf(v.x); o.y = f2bf(v.y); o.z = f2bf(v.z); o.w = f2bf(v.w);
        ((ushort4*)dst)[j] = o;
    }
}

// ---------- 2) QKV GEMM: 256x256 tile, BK=64, 8 waves, phase-split + counted vmcnt ----------
// C[4096][6144] = A[4096][4096] * W[6144][4096]^T, outputs scattered to q/k/v^T bf16.
// LDS 128KiB: A dbuf 2x32KB @0, B dbuf 2x32KB @65536. Swizzle: byte ^= (row&7)<<4.
// Stage order per K-tile (for tile t+1): p0:B[0,16K) p1:B[16K,32K) p2:A q0,q1 p3:A q2,q3
// where A qi = rows {32i..32i+31} U {128+32i..}. Reads: B fully at p0; A rows [32p,32p+32) at p.
// Counted vmcnt at phase end: p0:4 p1:5 p2:6 p3:3 (per-thread outstanding analysis; never 0).
#define GEMM_PHASE(PP, VNSTR, LOADB) do {                                                     \
    const int r0_ = wm*128 + (PP*2)*16 + lr16;                                                \
    bf16x8 a00 = *(const bf16x8*)(lds + cur*32768 + r0_*128 + ((lc4*16) ^ ((r0_&7)<<4)));     \
    bf16x8 a01 = *(const bf16x8*)(lds + cur*32768 + r0_*128 + ((64+lc4*16) ^ ((r0_&7)<<4)));  \
    const int r1_ = r0_ + 16;                                                                 \
    bf16x8 a10 = *(const bf16x8*)(lds + cur*32768 + r1_*128 + ((lc4*16) ^ ((r1_&7)<<4)));     \
    bf16x8 a11 = *(const bf16x8*)(lds + cur*32768 + r1_*128 + ((64+lc4*16) ^ ((r1_&7)<<4)));  \
    if (LOADB) {                                                                              \
        _Pragma("unroll")                                                                     \
        for (int ni = 0; ni < 4; ++ni) {                                                      \
            int rb = wn*64 + ni*16 + lr16;                                                    \
            bfr[ni][0] = *(const bf16x8*)(lds + 65536 + cur*32768 + rb*128 + ((lc4*16) ^ ((rb&7)<<4)));    \
            bfr[ni][1] = *(const bf16x8*)(lds + 65536 + cur*32768 + rb*128 + ((64+lc4*16) ^ ((rb&7)<<4))); \
        }                                                                                     \
    }                                                                                         \
    if (PP == 0)      { stageB(tb, ktn, tid*16);         stageB(tb, ktn, 8192 + tid*16);  }   \
    else if (PP == 1) { stageB(tb, ktn, 16384 + tid*16); stageB(tb, ktn, 24576 + tid*16); }   \
    else if (PP == 2) { stageA(tb, ktn, abase);          stageA(tb, ktn, abase + 4096);   }   \
    else              { stageA(tb, ktn, abase + 8192);   stageA(tb, ktn, abase + 12288);  }   \
    __builtin_amdgcn_s_barrier();                                                             \
    asm volatile("s_waitcnt lgkmcnt(0)" ::: "memory");                                        \
    __builtin_amdgcn_s_setprio(1);                                                            \
    _Pragma("unroll")                                                                         \
    for (int ni = 0; ni < 4; ++ni) {                                                          \
        acc[PP*2  ][ni] = __builtin_amdgcn_mfma_f32_16x16x32_bf16(a00, bfr[ni][0], acc[PP*2  ][ni], 0,0,0); \
        acc[PP*2  ][ni] = __builtin_amdgcn_mfma_f32_16x16x32_bf16(a01, bfr[ni][1], acc[PP*2  ][ni], 0,0,0); \
        acc[PP*2+1][ni] = __builtin_amdgcn_mfma_f32_16x16x32_bf16(a10, bfr[ni][0], acc[PP*2+1][ni], 0,0,0); \
        acc[PP*2+1][ni] = __builtin_amdgcn_mfma_f32_16x16x32_bf16(a11, bfr[ni][1], acc[PP*2+1][ni], 0,0,0); \
    }                                                                                         \
    __builtin_amdgcn_s_setprio(0);                                                            \
    asm volatile("s_waitcnt " VNSTR ::: "memory");                                            \
    __builtin_amdgcn_s_barrier();                                                             \
} while (0)

__global__ __launch_bounds__(512) void gemm_qkv8(
    const unsigned short* __restrict__ A, const unsigned short* __restrict__ W,
    unsigned short* __restrict__ qb, unsigned short* __restrict__ kb, unsigned short* __restrict__ vt)
{
    __shared__ unsigned char lds[131072];
    const int bid0 = blockIdx.x;
    const int swz = (bid0 & 7) * 48 + (bid0 >> 3);   // bijective XCD swizzle (384 % 8 == 0)
    const int bm = swz & 15, bn = swz >> 4;
    const int tid = threadIdx.x, l = tid & 63, w = tid >> 6;
    const int wm = w >> 2, wn = w & 3;
    const int lr16 = l & 15, lc4 = l >> 4;
    const int abase = (tid >> 8) * 16384 + (tid & 255) * 16;

    f32x4 acc[8][4] = {};
    bf16x8 bfr[4][2];

    auto stageB = [&](int tb, int ktn, int d) {
        int r = d >> 7, c = d & 127;
        int cs = c ^ ((r & 7) << 4);
        glds16(W + (long long)(bn * 256 + r) * CDIM + ktn * 64 + (cs >> 1),
               lds + 65536 + tb * 32768 + d);
    };
    auto stageA = [&](int tb, int ktn, int d) {
        int r = d >> 7, c = d & 127;
        int cs = c ^ ((r & 7) << 4);
        glds16(A + (long long)(bm * 256 + r) * CDIM + ktn * 64 + (cs >> 1),
               lds + tb * 32768 + d);
    };

    // prologue: stage tile 0 fully, drain once
    stageB(0, 0, tid * 16);         stageB(0, 0, 8192 + tid * 16);
    stageB(0, 0, 16384 + tid * 16); stageB(0, 0, 24576 + tid * 16);
    stageA(0, 0, abase);            stageA(0, 0, abase + 4096);
    stageA(0, 0, abase + 8192);     stageA(0, 0, abase + 12288);
    asm volatile("s_waitcnt vmcnt(0)" ::: "memory");
    __builtin_amdgcn_s_barrier();

    for (int t = 0; t < 64; ++t) {
        const int cur = t & 1, tb = cur ^ 1;
        const int ktn = (t + 1 < 64) ? t + 1 : 63;   // clamp: last iter re-stages tile 63 (harmless, uniform vmcnt)
        GEMM_PHASE(0, "vmcnt(4)", 1);
        GEMM_PHASE(1, "vmcnt(5)", 0);
        GEMM_PHASE(2, "vmcnt(6)", 0);
        GEMM_PHASE(3, "vmcnt(3)", 0);
    }

    // epilogue: scatter q [B,NH,N,D], k [B,NKV,N,D], v^T [B,NKV,D,N] (block is uniformly q, k, or v)
    const int colq = bn * 256 + wn * 64;
#pragma unroll
    for (int mf = 0; mf < 8; ++mf) {
        int gm0 = bm * 256 + wm * 128 + mf * 16 + lc4 * 4;
        int b = gm0 >> 11, n0 = gm0 & 2047;
#pragma unroll
        for (int nf = 0; nf < 4; ++nf) {
            int coln = colq + nf * 16 + lr16;
            if (bn < 16) {
                unsigned short* dst = qb + (((long long)(b * NH + (coln >> 7)) * NSEQ + n0) << 7) + (coln & 127);
#pragma unroll
                for (int r = 0; r < 4; ++r) dst[(long long)r << 7] = f2bf(acc[mf][nf][r]);
            } else if (bn < 20) {
                int ck = coln - 4096;
                unsigned short* dst = kb + (((long long)(b * NKV + (ck >> 7)) * NSEQ + n0) << 7) + (ck & 127);
#pragma unroll
                for (int r = 0; r < 4; ++r) dst[(long long)r << 7] = f2bf(acc[mf][nf][r]);
            } else {
                int cv = coln - 5120;
                ushort4 o4;
                o4.x = f2bf(acc[mf][nf][0]); o4.y = f2bf(acc[mf][nf][1]);
                o4.z = f2bf(acc[mf][nf][2]); o4.w = f2bf(acc[mf][nf][3]);
                *(ushort4*)(vt + (((long long)(b * NKV + (cv >> 7)) * HD + (cv & 127)) << 11) + n0) = o4;
            }
        }
    }
}

// ---------- 3) RoPE (folds log2(e)/sqrt(128) into q for exp2-domain softmax) ----------
__global__ void rope_kernel(unsigned short* __restrict__ qb, unsigned short* __restrict__ kb,
                            const float* __restrict__ cosc, const float* __restrict__ sinc,
                            const int* __restrict__ pos) {
    int rowid = blockIdx.x * 4 + (threadIdx.x >> 6);
    int d = threadIdx.x & 63;
    int b = rowid / (40 * NSEQ);
    int rem = rowid % (40 * NSEQ);
    int head = rem / NSEQ, n = rem % NSEQ;
    unsigned short* p;
    float scale;
    if (head < NH) { p = qb + (((long long)(b * NH + head) * NSEQ + n) << 7); scale = 0.12751747934e0f; }
    else           { p = kb + (((long long)(b * NKV + (head - NH)) * NSEQ + n) << 7); scale = 1.0f; }
    int pid = pos[b * NSEQ + n];
    float c = cosc[pid * HD + d], s = sinc[pid * HD + d];
    float x0 = bf2f(p[d]), x1 = bf2f(p[d + 64]);
    p[d]      = f2bf((x0 * c - x1 * s) * scale);
    p[d + 64] = f2bf((x1 * c + x0 * s) * scale);
}

// ---------- 4) flash attention: 4 waves x 32 q-rows, swapped QK^T, in-reg softmax ----------
__global__ __launch_bounds__(256) void attn_kernel(
    const unsigned short* __restrict__ qb, const unsigned short* __restrict__ kb,
    const unsigned short* __restrict__ vt, const int* __restrict__ obs,
    float* __restrict__ out)
{
    __shared__ unsigned char k_tile[16384];
    __shared__ unsigned char v_tile[16384];

    const int bid = blockIdx.x;
    const int qt = 15 - (bid >> 6);
    const int bh = bid & 63;
    const int b = bh >> 5, h = bh & 31, kvh = h >> 2;
    const int t = threadIdx.x, l = t & 63, w = t >> 6;
    const int lr = l & 31, hi = l >> 5;
    const int swl = (l & 7) << 4;

    const unsigned short* Qb = qb + (((long long)(b * NH + h) * NSEQ + qt * 128 + w * 32) << 7);
    const unsigned short* Kb = kb + (((long long)(b * NKV + kvh) * NSEQ) << 7);
    const unsigned short* Vb = vt + (((long long)(b * NKV + kvh) * HD) << 11);

    bf16x8 qf[8];
#pragma unroll
    for (int dk = 0; dk < 8; ++dk)
        qf[dk] = *(const bf16x8*)(Qb + lr * 128 + dk * 16 + hi * 8);

    f32x16 o[4];
#pragma unroll
    for (int dt = 0; dt < 4; ++dt)
#pragma unroll
        for (int e = 0; e < 16; ++e) o[dt][e] = 0.f;
    float m_run = -1e30f, l_run = 0.f;

    const int qwmax = qt * 128 + w * 32 + 31;
    const int niter = 2 * qt + 2;

    for (int kt = 0; kt < niter; ++kt) {
#pragma unroll
        for (int i = 0; i < 4; ++i) {
            int byte = (i * 256 + t) * 16;
            { int r = byte >> 8, c = byte & 255; int cs = c ^ ((r & 7) << 4);
              glds16(Kb + (((long long)(kt * 64 + r)) << 7) + (cs >> 1), k_tile + byte); }
            { int r = byte >> 7, c = byte & 127; int cs = c ^ ((r & 7) << 4);
              glds16(Vb + (((long long)r) << 11) + kt * 64 + (cs >> 1), v_tile + byte); }
        }
        __syncthreads();

        if (kt * 64 <= qwmax) {
            f32x16 s0, s1;
#pragma unroll
            for (int e = 0; e < 16; ++e) { s0[e] = 0.f; s1[e] = 0.f; }
            __builtin_amdgcn_s_setprio(1);
#pragma unroll
            for (int dk = 0; dk < 8; ++dk) {
                int cb = (dk * 32 + hi * 16) ^ swl;
                bf16x8 k0 = *(const bf16x8*)(k_tile + lr * 256 + cb);
                bf16x8 k1 = *(const bf16x8*)(k_tile + (32 + lr) * 256 + cb);
                s0 = __builtin_amdgcn_mfma_f32_32x32x16_bf16(k0, qf[dk], s0, 0, 0, 0);
                s1 = __builtin_amdgcn_mfma_f32_32x32x16_bf16(k1, qf[dk], s1, 0, 0, 0);
            }
            __builtin_amdgcn_s_setprio(0);

            if (kt * 64 + 63 > qt * 128 + w * 32) {
                int qg = qt * 128 + w * 32 + lr;
                int base = kt * 64 + hi * 4;
#pragma unroll
                for (int e = 0; e < 16; ++e) {
                    int kv0 = base + (e & 3) + 8 * (e >> 2);
                    if (kv0 > qg)      s0[e] = -1e30f;
                    if (kv0 + 32 > qg) s1[e] = -1e30f;
                }
            }

            float mloc = fmaxf(s0[0], s0[1]);
#pragma unroll
            for (int e = 2; e < 16; ++e) mloc = fmaxf(mloc, s0[e]);
#pragma unroll
            for (int e = 0; e < 16; ++e) mloc = fmaxf(mloc, s1[e]);
            mloc = fmaxf(mloc, __shfl_xor(mloc, 32));

            float mm = m_run;
            if (!__all(mloc - m_run <= 8.f)) {
                mm = fmaxf(m_run, mloc);
                float sc = __builtin_amdgcn_exp2f(m_run - mm);
                l_run *= sc;
#pragma unroll
                for (int dt = 0; dt < 4; ++dt)
#pragma unroll
                    for (int e = 0; e < 16; ++e) o[dt][e] *= sc;
                m_run = mm;
            }
            float sum = 0.f;
#pragma unroll
            for (int e = 0; e < 16; ++e) { s0[e] = __builtin_amdgcn_exp2f(s0[e] - mm); sum += s0[e]; }
#pragma unroll
            for (int e = 0; e < 16; ++e) { s1[e] = __builtin_amdgcn_exp2f(s1[e] - mm); sum += s1[e]; }
            sum += __shfl_xor(sum, 32);
            l_run += sum;

            bf16x8 pb[4];
            pack_tile(s0, l, pb[0], pb[1]);
            pack_tile(s1, l, pb[2], pb[3]);

            __builtin_amdgcn_s_setprio(1);
#pragma unroll
            for (int dt = 0; dt < 4; ++dt) {
#pragma unroll
                for (int kk = 0; kk < 4; ++kk) {
                    int cb = (kk * 32 + hi * 16) ^ swl;
                    bf16x8 vf = *(const bf16x8*)(v_tile + (dt * 32 + lr) * 128 + cb);
                    o[dt] = __builtin_amdgcn_mfma_f32_32x32x16_bf16(vf, pb[kk], o[dt], 0, 0, 0);
                }
            }
            __builtin_amdgcn_s_setprio(0);
        }
        __syncthreads();
    }

    {
        int n = qt * 128 + w * 32 + lr;
        float fac = (1.f / l_run) * ((obs[b * NSEQ + n] == 1) ? 1.f : 0.f);
        unsigned char* slice = k_tile + w * 4096;
        int q2 = l >> 1, half = l & 1;
        long long orow = ((long long)(b * NSEQ + qt * 128 + w * 32 + q2)) << 12;
#pragma unroll
        for (int dt = 0; dt < 4; ++dt) {
#pragma unroll
            for (int e = 0; e < 16; e += 2) {
                int dl = (e & 3) + 8 * (e >> 2) + hi * 4;
                int byte = (lr * 128 + dl * 4) ^ ((lr & 7) << 4);
                *(float2*)(slice + byte) = make_float2(o[dt][e] * fac, o[dt][e + 1] * fac);
            }
#pragma unroll
            for (int j = 0; j < 4; ++j) {
                int byte = (q2 * 128 + half * 64 + j * 16) ^ ((q2 & 7) << 4);
                f32x4 vv = *(const f32x4*)(slice + byte);
                *(f32x4*)(out + orow + h * 128 + dt * 32 + half * 16 + j * 4) = vv;
            }
            __syncthreads();
        }
    }
}

// ---------- launch ----------
extern "C" void kernel_launch(void* const* d_in, const int* in_sizes, int n_in,
                              void* d_out, int out_size, void* d_ws, size_t ws_size,
                              hipStream_t stream) {
    (void)in_sizes; (void)n_in; (void)out_size; (void)ws_size;
    const float* inp  = (const float*)d_in[0];
    const float* wgt  = (const float*)d_in[1];
    const float* cosc = (const float*)d_in[2];
    const float* sinc = (const float*)d_in[3];
    const int* pos = (const int*)d_in[5];
    const int* obs = (const int*)d_in[6];
    float* out = (float*)d_out;

    char* ws = (char*)d_ws;
    unsigned short* A16 = (unsigned short*)(ws);
    unsigned short* W16 = (unsigned short*)(ws + 33554432LL);
    unsigned short* qb  = (unsigned short*)(ws + 83886080LL);
    unsigned short* kb  = (unsigned short*)(ws + 117440512LL);
    unsigned short* vt  = (unsigned short*)(ws + 125829120LL);

    convert_kernel<<<2048, 256, 0, stream>>>(inp, wgt, A16, W16);
    gemm_qkv8<<<384, 512, 0, stream>>>(A16, W16, qb, kb, vt);
    rope_kernel<<<(2 * 40 * NSEQ) / 4, 256, 0, stream>>>(qb, kb, cosc, sinc, pos);
    attn_kernel<<<16 * 64, 256, 0, stream>>>(qb, kb, vt, obs, out);
}